// Round 5
// baseline (154.809 us; speedup 1.0000x reference)
//
#include <hip/hip_runtime.h>

typedef __bf16 bf16x8 __attribute__((ext_vector_type(8)));
typedef __bf16 bf16x4 __attribute__((ext_vector_type(4)));
typedef float f32x4 __attribute__((ext_vector_type(4)));

__device__ __forceinline__ void async_copy16(const void* g, void* l) {
    __builtin_amdgcn_global_load_lds(
        (const __attribute__((address_space(1))) void*)g,
        (__attribute__((address_space(3))) void*)l, 16, 0, 0);
}

// ---------------- cvt: x -> bf16, [Wq;Wk] -> bf16, [bq;bk] -> f32 concat ----
__global__ __launch_bounds__(256) void cvt_kernel(
    const float4* __restrict__ x, const float4* __restrict__ Wq,
    const float4* __restrict__ Wk, const float4* __restrict__ bq,
    const float4* __restrict__ bk,
    bf16x4* __restrict__ xb, bf16x4* __restrict__ Wb,
    float4* __restrict__ biasc) {
    int i = blockIdx.x * 256 + threadIdx.x;
    if (i < 2097152) {
        float4 v = x[i];
        bf16x4 r = {(__bf16)v.x, (__bf16)v.y, (__bf16)v.z, (__bf16)v.w};
        xb[i] = r;
    }
    if (i < 131072) {
        float4 v = (i < 65536) ? Wq[i] : Wk[i - 65536];
        bf16x4 r = {(__bf16)v.x, (__bf16)v.y, (__bf16)v.z, (__bf16)v.w};
        Wb[i] = r;
    }
    if (i < 256) {
        biasc[i] = (i < 128) ? bq[i] : bk[i - 128];
    }
}

// ---------------- fold: xzT[b][d][s] = bf16(x[b][Q(s)][d] / Z_s[s]) --------
// n-dim stored in permuted order: storage s holds logical n = Q(s),
// Q(s) (within 64-group) = ((s&3)<<4) | ((s>>2)&15). Z is storage-indexed.
__global__ __launch_bounds__(256) void fold_kernel(
    const __bf16* __restrict__ xb, const float* __restrict__ Z,
    ushort* __restrict__ xzT) {
    __shared__ float tile[64][65];
    __shared__ float zin[64];
    const int b = blockIdx.y;
    const int td = blockIdx.x & 7;    // d-tile (512/64 = 8)
    const int tn = blockIdx.x >> 3;   // n-tile (2048/64 = 32)
    const int n0 = tn * 64, d0 = td * 64;
    const int t = threadIdx.x;
    if (t < 64) zin[t] = 1.0f / Z[b * 2048 + n0 + t];  // storage order
    __syncthreads();
    const int cl = t & 15, c4 = cl * 4, rr = t >> 4;
    // fill: logical rows (raw x values)
#pragma unroll
    for (int j = 0; j < 4; ++j) {
        int nr = rr + j * 16;
        bf16x4 v = *(const bf16x4*)&xb[((size_t)b * 2048 + n0 + nr) * 512 + d0 + c4];
        tile[nr][c4 + 0] = (float)v[0];
        tile[nr][c4 + 1] = (float)v[1];
        tile[nr][c4 + 2] = (float)v[2];
        tile[nr][c4 + 3] = (float)v[3];
    }
    __syncthreads();
    // write: storage positions c4..c4+3 hold logical rows j*16+cl
#pragma unroll
    for (int j2 = 0; j2 < 4; ++j2) {
        int dr = rr + j2 * 16;
        bf16x4 pk;
#pragma unroll
        for (int j = 0; j < 4; ++j)
            pk[j] = (__bf16)(tile[j * 16 + cl][dr] * zin[c4 + j]);
        *(bf16x4*)&xzT[((size_t)b * 512 + d0 + dr) * 2048 + n0 + c4] = pk;
    }
}

// ---------------- bt-GEMM: C[m,n] = sum_k A[m,k]*B[n,k]  (r1-proven core) --
// 128x128 tile, BK=64, 4 waves (2x2), 16x16x32 MFMA. Single 32KB LDS stage,
// swizzle involution both sides: kbyte ^= ((row&7)<<4).
// EPI 0/1 store with per-64-col permutation P(n)=((n&15)<<2)|((n>>4)&3):
// lane cl's four j-values are contiguous -> one 8B packed store per (i,q).
// EPI 0: +bias (logical), bf16 perm-store
// EPI 1: exp(acc*scale), bf16 perm-store + storage-indexed Z col-sums
// EPI 2: f32 store, natural layout (output)
template <int EPI>
__global__ __launch_bounds__(256) void gemm_bt(
    const ushort* __restrict__ A, int lda, long sA,
    const ushort* __restrict__ B, int ldb, long sB,
    void* __restrict__ C, int ldc, long sC,
    int tiles_n, int K,
    const float* __restrict__ bias, float scale,
    float* __restrict__ Z, long sZ) {
    __shared__ ushort lA[128 * 64];  // 16 KB
    __shared__ ushort lB[128 * 64];  // 16 KB
    const int b = blockIdx.y;
    A += (size_t)b * sA;
    B += (size_t)b * sB;
    const int tm = blockIdx.x / tiles_n, tn = blockIdx.x % tiles_n;
    const int t = threadIdx.x;
    const int l = t & 63, w = t >> 6;
    const int wr = w >> 1, wc = w & 1;  // 2x2 waves, each 64x64

    f32x4 acc[4][4];
#pragma unroll
    for (int i = 0; i < 4; ++i)
#pragma unroll
        for (int j = 0; j < 4; ++j) acc[i][j] = (f32x4){0.f, 0.f, 0.f, 0.f};

    for (int k0 = 0; k0 < K; k0 += 64) {
#pragma unroll
        for (int p = 0; p < 4; ++p) {
            int off = p * 4096 + t * 16;
            int row = off >> 7;
            int kb = off & 127;
            int kswz = kb ^ ((row & 7) << 4);
            async_copy16(A + (size_t)(tm * 128 + row) * lda + k0 + (kswz >> 1),
                         (char*)lA + off);
            async_copy16(B + (size_t)(tn * 128 + row) * ldb + k0 + (kswz >> 1),
                         (char*)lB + off);
        }
        __syncthreads();
#pragma unroll
        for (int ks = 0; ks < 2; ++ks) {
            bf16x8 af[4], bfr[4];
#pragma unroll
            for (int i = 0; i < 4; ++i) {
                int row = wr * 64 + i * 16 + (l & 15);
                int colb = (ks * 64 + (l >> 4) * 16) ^ ((row & 7) << 4);
                af[i] = *(const bf16x8*)((const char*)lA + row * 128 + colb);
            }
#pragma unroll
            for (int j = 0; j < 4; ++j) {
                int row = wc * 64 + j * 16 + (l & 15);
                int colb = (ks * 64 + (l >> 4) * 16) ^ ((row & 7) << 4);
                bfr[j] = *(const bf16x8*)((const char*)lB + row * 128 + colb);
            }
#pragma unroll
            for (int i = 0; i < 4; ++i)
#pragma unroll
                for (int j = 0; j < 4; ++j)
                    acc[i][j] = __builtin_amdgcn_mfma_f32_16x16x32_bf16(
                        af[i], bfr[j], acc[i][j], 0, 0, 0);
        }
        __syncthreads();
    }

    const int mb = tm * 128 + wr * 64;
    const int nb = tn * 128 + wc * 64;
    const int cl = l & 15;

    if (EPI == 0) {
        ushort* Cp = (ushort*)C + (size_t)b * sC;
#pragma unroll
        for (int i = 0; i < 4; ++i)
#pragma unroll
            for (int q = 0; q < 4; ++q) {
                int row = mb + i * 16 + (l >> 4) * 4 + q;
                bf16x4 pk;
#pragma unroll
                for (int j = 0; j < 4; ++j)
                    pk[j] = (__bf16)(acc[i][j][q] + bias[nb + j * 16 + cl]);
                *(bf16x4*)&Cp[(size_t)row * ldc + nb + cl * 4] = pk;
            }
    } else if (EPI == 1) {
        ushort* Cp = (ushort*)C + (size_t)b * sC;
        float colsum[4] = {0.f, 0.f, 0.f, 0.f};
#pragma unroll
        for (int i = 0; i < 4; ++i)
#pragma unroll
            for (int q = 0; q < 4; ++q) {
                int row = mb + i * 16 + (l >> 4) * 4 + q;
                bf16x4 pk;
#pragma unroll
                for (int j = 0; j < 4; ++j) {
                    float e = __expf(acc[i][j][q] * scale);
                    colsum[j] += e;
                    pk[j] = (__bf16)e;
                }
                *(bf16x4*)&Cp[(size_t)row * ldc + nb + cl * 4] = pk;
            }
#pragma unroll
        for (int j = 0; j < 4; ++j) {
            float s = colsum[j];
            s += __shfl_xor(s, 16);
            s += __shfl_xor(s, 32);
            if (l < 16) atomicAdd(&Z[b * sZ + nb + l * 4 + j], s);
        }
    } else {
        float* Cp = (float*)C + (size_t)b * sC;
#pragma unroll
        for (int i = 0; i < 4; ++i)
#pragma unroll
            for (int j = 0; j < 4; ++j)
#pragma unroll
                for (int q = 0; q < 4; ++q) {
                    int row = mb + i * 16 + (l >> 4) * 4 + q;
                    int col = nb + j * 16 + cl;
                    Cp[(size_t)row * ldc + col] = acc[i][j][q];
                }
    }
}

extern "C" void kernel_launch(void* const* d_in, const int* in_sizes, int n_in,
                              void* d_out, int out_size, void* d_ws, size_t ws_size,
                              hipStream_t stream) {
    const float* x  = (const float*)d_in[0];
    const float* Wq = (const float*)d_in[1];
    const float* bq = (const float*)d_in[2];
    const float* Wk = (const float*)d_in[3];
    const float* bk = (const float*)d_in[4];

    char* ws = (char*)d_ws;
    ushort* xb    = (ushort*)(ws);                 // 16 MB
    ushort* Wb    = (ushort*)(ws + 16777216);      //  1 MB
    float*  biasc = (float*) (ws + 17825792);      //  4 KB
    float*  Z     = (float*) (ws + 17829888);      // 64 KB (storage-indexed)
    ushort* qkb   = (ushort*)(ws + 17895424);      // 32 MB (reused as xzT)
    ushort* E     = (ushort*)(ws + 51449856);      // 64 MB
    ushort* xzT   = qkb;   // qkb dead after E-pass

    hipMemsetAsync(Z, 0, 16384 * 4, stream);

    cvt_kernel<<<8192, 256, 0, stream>>>(
        (const float4*)x, (const float4*)Wq, (const float4*)Wk,
        (const float4*)bq, (const float4*)bk,
        (bf16x4*)xb, (bf16x4*)Wb, (float4*)biasc);

    // proj: qk[m, P(h)] = x[m,:] . W[h,:] + bias[h]   (M=16384, N=1024, K=512)
    gemm_bt<0><<<dim3(1024, 1), 256, 0, stream>>>(
        xb, 512, 0L, Wb, 512, 0L, qkb, 1024, 0L,
        8, 512, biasc, 0.f, nullptr, 0L);

    // E-pass: E[b][m][P(n)] = exp(scale * k[m].q[n]); Z_s += col sums
    // (k-dim of this GEMM = h-storage; permutation cancels between A and B)
    gemm_bt<1><<<dim3(256, 8), 256, 0, stream>>>(
        qkb + 512, 1024, 2048L * 1024, qkb, 1024, 2048L * 1024,
        E, 2048, 2048L * 2048, 16, 512,
        nullptr, 0.04419417382415922f, Z, 2048L);

    // fold: xzT[b][d][s] = bf16(x[b][Q(s)][d] / Z_s[s])
    fold_kernel<<<dim3(256, 8), 256, 0, stream>>>((const __bf16*)xb, Z, xzT);

    // out: out[b][m][d] = sum_s E[b][m][s] * xzT[b][d][s]   (fp32 store)
    gemm_bt<2><<<dim3(64, 8), 256, 0, stream>>>(
        E, 2048, 2048L * 2048, xzT, 2048, 512L * 2048,
        d_out, 512, 2048L * 512, 4, 2048,
        nullptr, 0.f, nullptr, 0L);
}